// Round 13
// baseline (163.777 us; speedup 1.0000x reference)
//
#include <hip/hip_runtime.h>
#include <hip/hip_bf16.h>
#include <math.h>

typedef __attribute__((ext_vector_type(4))) float  f32x4;
typedef __attribute__((ext_vector_type(8))) __bf16 bf16x8;

#define LN_EPS 1e-6f

// ---------- small math helpers ----------
__device__ __forceinline__ float sigf(float v){ return 1.f / (1.f + __expf(-v)); }
__device__ __forceinline__ float tanh_f(float v){
  float t = __expf(-2.f * fabsf(v));
  float r = (1.f - t) / (1.f + t);
  return copysignf(r, v);
}
__device__ __forceinline__ float wave_sum(float v){
  #pragma unroll
  for(int m = 1; m < 64; m <<= 1) v += __shfl_xor(v, m, 64);
  return v;
}

// f32 -> bf16 via hardware cvt (RNE); pairs fuse into v_cvt_pk_bf16_f32
__device__ __forceinline__ unsigned short f2bf(float f){
  return __builtin_bit_cast(unsigned short, static_cast<__bf16>(f));
}
__device__ __forceinline__ unsigned int pk_bf16(float a, float b){
  return (unsigned int)f2bf(a) | ((unsigned int)f2bf(b) << 16);
}
__device__ __forceinline__ float bfu(unsigned int u){  // low 16 bits = bf16
  unsigned int t = u << 16;
  return __builtin_bit_cast(float, t);
}

// ---------- fused reg staging (load f32 + cvt + swizzled ds_write) ----------
// LDS layout: row-major [NROWS][64] bf16 (128 B/row), byte ^= (row&7)<<4
template<int NROWS, int NTHR>
__device__ __forceinline__ void stage_tile(const float* __restrict__ src, int row_stride,
                                           unsigned short* lds, int tid){
  constexpr int PER = (NROWS * 16) / NTHR;   // float4's per thread
  #pragma unroll
  for(int s = 0; s < PER; ++s){
    int fi  = tid + s * NTHR;
    int row = fi >> 4, kf = fi & 15;
    float4 v = *(reinterpret_cast<const float4*>(src + row * row_stride) + kf);
    unsigned int lo = pk_bf16(v.x, v.y), hi = pk_bf16(v.z, v.w);
    int byte = ((row << 7) + (kf << 3)) ^ ((row & 7) << 4);
    uint2 u; u.x = lo; u.y = hi;
    *reinterpret_cast<uint2*>(reinterpret_cast<char*>(lds) + byte) = u;
  }
}

// ---------- DMA staging: bf16 global -> LDS via global_load_lds (16B) ----------
// LDS dest linear (wave-uniform base; HW adds lane*16); XOR swizzle applied to
// the per-lane GLOBAL source granule (rule #21 / m173 pattern).
template<int NROWS, int NTHR>
__device__ __forceinline__ void dma_tile(const unsigned short* __restrict__ src,
                                         int row_stride_elems,
                                         unsigned short* lds, int tid){
  constexpr int PER = (NROWS * 8) / NTHR;    // 16B granules per thread
  #pragma unroll
  for(int s = 0; s < PER; ++s){
    int G   = tid + s * NTHR;
    int r   = G >> 3;
    int kf2 = (G & 7) ^ (r & 7);
    const char* gp = reinterpret_cast<const char*>(src + r * row_stride_elems) + kf2 * 16;
    char* lp = reinterpret_cast<char*>(lds) + ((tid & ~63) + s * NTHR) * 16;
    __builtin_amdgcn_global_load_lds(
        (const __attribute__((address_space(1))) unsigned int*)gp,
        (__attribute__((address_space(3))) unsigned int*)lp, 16, 0, 0);
  }
}

// read one 16x32 MFMA operand fragment (swizzled layout)
__device__ __forceinline__ bf16x8 read_frag(const unsigned short* lds, int row, int ks, int lane){
  int byte = ((row << 7) + ((ks + ((lane >> 4) << 3)) << 1)) ^ ((row & 7) << 4);
  return *reinterpret_cast<const bf16x8*>(reinterpret_cast<const char*>(lds) + byte);
}

// =====================================================================
// K0: convert Wih|Whh|x|h (f32) -> contiguous bf16 pool.
// 2176 blocks x 256 thr x 8 slot-major units (exact cover, block-aligned
// regions). Per thread: 16 independent 16B loads in flight, then 8 x 16B
// stores. Slot-major -> each slot is a fully coalesced 4KB/wave access.
// =====================================================================
__global__ __launch_bounds__(256) void kconv(
    const float* __restrict__ Wih, const float* __restrict__ Whh,
    const float* __restrict__ x, const float* __restrict__ h,
    unsigned short* __restrict__ dst){
  int tid = threadIdx.x;
  long bid = blockIdx.x;
  const float* src; long rbase;
  if(bid < 1024)      { src = Wih; rbase = 0; }
  else if(bid < 2048) { src = Whh; rbase = 2097152; }
  else if(bid < 2112) { src = x;   rbase = 4194304; }
  else                { src = h;   rbase = 4325376; }
  long base = bid * 2048;
  float4 a[8], b[8];
  #pragma unroll
  for(int s = 0; s < 8; ++s){
    long off = base + s * 256 + tid - rbase;   // unit offset within region
    a[s] = reinterpret_cast<const float4*>(src)[2 * off];
    b[s] = reinterpret_cast<const float4*>(src)[2 * off + 1];
  }
  #pragma unroll
  for(int s = 0; s < 8; ++s){
    long i = base + s * 256 + tid;             // global unit index in pool
    uint4 o;
    o.x = pk_bf16(a[s].x, a[s].y); o.y = pk_bf16(a[s].z, a[s].w);
    o.z = pk_bf16(b[s].x, b[s].y); o.w = pk_bf16(b[s].z, b[s].w);
    reinterpret_cast<uint4*>(dst)[i] = o;
  }
}

// =====================================================================
// K1: v = [x | h | hyper_h] @ [hc_Wih | hc_Whh]^T   (512 x 1024, K=4352)
// K split in 2 halves across block roles -> 1024 blocks; bf16 halves to v1/v2.
// =====================================================================
__global__ __launch_bounds__(256, 2) void k1_hyper_gemm(
    const float* __restrict__ x, const float* __restrict__ h,
    const float* __restrict__ hyper_h, const float* __restrict__ hc_Wih,
    const float* __restrict__ hc_Whh,
    unsigned short* __restrict__ v1, unsigned short* __restrict__ v2){
  __shared__ unsigned short Ab[32 * 64];
  __shared__ unsigned short Bb[32 * 64];
  int tid = threadIdx.x, lane = tid & 63, w = tid >> 6;
  int wr = w >> 1, wc = w & 1;
  int fid = blockIdx.x;
  int half = fid >> 9, rid = fid & 511;
  int n0 = (rid & 31) * 32, m0 = (rid >> 5) * 32;
  unsigned short* vo = half ? v2 : v1;
  int kb = half * 2176;
  f32x4 acc = {0.f, 0.f, 0.f, 0.f};

  #pragma unroll 1
  for(int kk = 0; kk < 2176; kk += 64){
    int k0 = kb + kk;
    const float* as; int ast;
    if(k0 < 2048)      { as = x       + m0 * 2048 + k0;          ast = 2048; }
    else if(k0 < 4096) { as = h       + m0 * 2048 + (k0 - 2048); ast = 2048; }
    else               { as = hyper_h + m0 * 256  + (k0 - 4096); ast = 256;  }
    const float* bs; int bst;
    if(k0 < 4096)      { bs = hc_Wih  + n0 * 4096 + k0;          bst = 4096; }
    else               { bs = hc_Whh  + n0 * 256  + (k0 - 4096); bst = 256;  }
    __syncthreads();
    stage_tile<32, 256>(as, ast, Ab, tid);
    stage_tile<32, 256>(bs, bst, Bb, tid);
    __syncthreads();
    #pragma unroll
    for(int ks = 0; ks < 64; ks += 32){
      bf16x8 af = read_frag(Ab, wr * 16 + (lane & 15), ks, lane);
      bf16x8 bf = read_frag(Bb, wc * 16 + (lane & 15), ks, lane);
      acc = __builtin_amdgcn_mfma_f32_16x16x32_bf16(af, bf, acc, 0, 0, 0);
    }
  }
  int n = n0 + wc * 16 + (lane & 15);
  #pragma unroll
  for(int r = 0; r < 4; ++r){
    int m = m0 + wr * 16 + (lane >> 4) * 4 + r;
    vo[m * 1024 + n] = f2bf(acc[r]);
  }
}

// =====================================================================
// K2: v = v1 + v2 + hc_bih, hyper LN + hyper LSTM cell. 1 wave per row.
// =====================================================================
__global__ __launch_bounds__(256) void k2_hyper_cell(
    const unsigned short* __restrict__ v1, const unsigned short* __restrict__ v2,
    const float* __restrict__ bih, const float* __restrict__ hyper_c,
    const float* __restrict__ lng, const float* __restrict__ lnb,
    const float* __restrict__ lncg, const float* __restrict__ lncb,
    float* __restrict__ out){
  int tid = threadIdx.x, lane = tid & 63, w = tid >> 6;
  int b = blockIdx.x * 4 + w;
  float vn[4][4];
  #pragma unroll
  for(int g = 0; g < 4; ++g){
    float vv[4], s = 0.f;
    #pragma unroll
    for(int q = 0; q < 4; ++q){
      int e = lane + 64 * q;
      int bi = b * 1024 + g * 256 + e;
      vv[q] = bfu(v1[bi]) + bfu(v2[bi]) + bih[g * 256 + e];
      s += vv[q];
    }
    float mean = wave_sum(s) * (1.f / 256.f);
    float sse = 0.f;
    #pragma unroll
    for(int q = 0; q < 4; ++q){ float d = vv[q] - mean; sse += d * d; }
    float inv = 1.f / (sqrtf(wave_sum(sse) * (1.f / 255.f)) + LN_EPS);
    #pragma unroll
    for(int q = 0; q < 4; ++q){
      int e = lane + 64 * q;
      vn[g][q] = lng[g * 256 + e] * (vv[q] - mean) * inv + lnb[g * 256 + e];
    }
  }
  float ncr[4], os[4], s2 = 0.f;
  #pragma unroll
  for(int q = 0; q < 4; ++q){
    float hc = hyper_c[b * 256 + lane + 64 * q];
    float hi = vn[0][q], hf = vn[1][q] + 1.f, hg = vn[2][q], ho = vn[3][q];
    ncr[q] = hc * sigf(hf) + sigf(hi) * tanh_f(hg);
    os[q]  = sigf(ho);
    s2 += ncr[q];
  }
  float mean2 = wave_sum(s2) * (1.f / 256.f);
  float sse2 = 0.f;
  #pragma unroll
  for(int q = 0; q < 4; ++q){ float d = ncr[q] - mean2; sse2 += d * d; }
  float inv2 = 1.f / (sqrtf(wave_sum(sse2) * (1.f / 255.f)) + LN_EPS);
  #pragma unroll
  for(int q = 0; q < 4; ++q){
    int e = lane + 64 * q;
    float ncn = lncg[e] * (ncr[q] - mean2) * inv2 + lncb[e];
    out[2097152 + b * 256 + e] = tanh_f(ncn) * os[q];  // new_hyper_h
    out[2228224 + b * 256 + e] = ncn;                  // new_hyper_c
  }
}

// =====================================================================
// K3: P = nhh @ [Wph|Wpx|Wpb]^T + [bph|bpx|0]   (512 x 768, K=256)
// =====================================================================
__global__ __launch_bounds__(256, 2) void k3_pmat(
    const float* __restrict__ nhh, const float* __restrict__ Wph,
    const float* __restrict__ Wpx, const float* __restrict__ Wpb,
    const float* __restrict__ bph, const float* __restrict__ bpx,
    float* __restrict__ P){
  __shared__ unsigned short Ab[64 * 64];
  __shared__ unsigned short Bb[64 * 64];
  int tid = threadIdx.x, lane = tid & 63, w = tid >> 6;
  int wr = w >> 1, wc = w & 1;
  int n0 = blockIdx.x * 64, m0 = blockIdx.y * 64;
  int j3 = n0 >> 8, jr0 = n0 & 255;
  const float* W = (j3 == 0) ? Wph : (j3 == 1) ? Wpx : Wpb;
  f32x4 acc[2][2];
  const f32x4 zf = {0.f, 0.f, 0.f, 0.f};
  #pragma unroll
  for(int i = 0; i < 2; ++i){ acc[i][0] = zf; acc[i][1] = zf; }

  #pragma unroll 1
  for(int k0 = 0; k0 < 256; k0 += 64){
    __syncthreads();
    stage_tile<64, 256>(nhh + m0 * 256 + k0, 256, Ab, tid);
    stage_tile<64, 256>(W + jr0 * 256 + k0, 256, Bb, tid);
    __syncthreads();
    #pragma unroll
    for(int ks = 0; ks < 64; ks += 32){
      bf16x8 af[2], bfr[2];
      #pragma unroll
      for(int i = 0; i < 2; ++i) af[i]  = read_frag(Ab, wr * 32 + i * 16 + (lane & 15), ks, lane);
      #pragma unroll
      for(int j = 0; j < 2; ++j) bfr[j] = read_frag(Bb, wc * 32 + j * 16 + (lane & 15), ks, lane);
      #pragma unroll
      for(int i = 0; i < 2; ++i){
        #pragma unroll
        for(int j = 0; j < 2; ++j)
          acc[i][j] = __builtin_amdgcn_mfma_f32_16x16x32_bf16(af[i], bfr[j], acc[i][j], 0, 0, 0);
      }
    }
  }
  #pragma unroll
  for(int j = 0; j < 2; ++j){
    int cj = jr0 + wc * 32 + j * 16 + (lane & 15);
    float bv = (j3 == 0) ? bph[cj] : (j3 == 1) ? bpx[cj] : 0.f;
    int n = n0 + wc * 32 + j * 16 + (lane & 15);
    #pragma unroll
    for(int i = 0; i < 2; ++i){
      #pragma unroll
      for(int r = 0; r < 4; ++r){
        int m = m0 + wr * 32 + i * 16 + (lane >> 4) * 4 + r;
        P[m * 768 + n] = acc[i][j][r] + bv;
      }
    }
  }
}

// =====================================================================
// K4 (DMA + counted vmcnt, T4): role-split, 512 blocks x 512 thr (2/CU),
// 128x128 tile, 8 waves (4x2), BK=64, LDS double-buffer 64 KB.
// Per step: {vmcnt(4) [tile t landed, t+1 in flight]; s_barrier;
//            MFMA tile t; lgkmcnt(0); s_barrier; issue dma tile t+2}.
// Loads stay in flight ACROSS barriers (never drained to 0 mid-loop).
// =====================================================================
__global__ __launch_bounds__(512, 2) void k4_gates_dma(
    const unsigned short* __restrict__ xbf, const unsigned short* __restrict__ hbf,
    const unsigned short* __restrict__ Wihbf, const unsigned short* __restrict__ Whhbf,
    const float* __restrict__ bias, const float* __restrict__ P,
    const float* __restrict__ Wsh, const float* __restrict__ Wsx,
    const float* __restrict__ Wsb,
    unsigned short* __restrict__ g1, unsigned short* __restrict__ g2){
  __shared__ unsigned short Ab[2][128 * 64];   // 2 x 16 KB
  __shared__ unsigned short Bb[2][128 * 64];   // 2 x 16 KB
  int tid = threadIdx.x, lane = tid & 63, w = tid >> 6;
  int wr = w >> 1, wc = w & 1;                 // 4x2 wave grid, wave tile 32x64
  int fid = blockIdx.x;                        // 512 blocks
  int role = fid >> 8;
  int rid = fid & 255;
  int xcd = rid & 7, idx = rid >> 3;           // idx 0..31
  int nt = xcd * 8 + (idx >> 2);               // n-tile 0..63 (8 per XCD)
  int mt = idx & 3;                            // m-tile 0..3
  int n0 = nt << 7, m0 = mt << 7;
  int g = n0 >> 11, hc0 = n0 & 2047;

  const unsigned short* V = role ? hbf : xbf;
  const unsigned short* W = role ? Whhbf : Wihbf;
  const float* Pm = P + m0 * 768 + (role ? 0 : 256) + g * 64;
  const float* Ws = (role ? Wsh : Wsx) + (g * 2048 + hc0) * 64;

  f32x4 accZ[2][4], accW[2][4];
  auto zero = [&](f32x4 (&a)[2][4]){
    const f32x4 zf = {0.f, 0.f, 0.f, 0.f};
    #pragma unroll
    for(int i = 0; i < 2; ++i)
      #pragma unroll
      for(int j = 0; j < 4; ++j) a[i][j] = zf;
  };
  auto mfma_on = [&](const unsigned short* A_, const unsigned short* B_, f32x4 (&acc)[2][4]){
    #pragma unroll
    for(int ks = 0; ks < 64; ks += 32){
      bf16x8 af[2], bfr[4];
      #pragma unroll
      for(int i = 0; i < 2; ++i) af[i]  = read_frag(A_, wr * 32 + i * 16 + (lane & 15), ks, lane);
      #pragma unroll
      for(int j = 0; j < 4; ++j) bfr[j] = read_frag(B_, wc * 64 + j * 16 + (lane & 15), ks, lane);
      #pragma unroll
      for(int i = 0; i < 2; ++i){
        #pragma unroll
        for(int j = 0; j < 4; ++j)
          acc[i][j] = __builtin_amdgcn_mfma_f32_16x16x32_bf16(af[i], bfr[j], acc[i][j], 0, 0, 0);
      }
    }
  };

  zero(accZ); zero(accW);

  // ---- z mini-GEMM (reg-staged f32, once) in buf0 ----
  stage_tile<128, 512>(Pm, 768, Ab[0], tid);
  stage_tile<128, 512>(Ws, 64, Bb[0], tid);
  __syncthreads();
  mfma_on(Ab[0], Bb[0], accZ);
  __syncthreads();                              // all reads done; buffers free

  // ---- prologue: issue tiles 0 and 1 (4 loads/thread each; 8 outstanding) ----
  dma_tile<128, 512>(V + m0 * 2048, 2048, Ab[0], tid);
  dma_tile<128, 512>(W + n0 * 2048, 2048, Bb[0], tid);
  dma_tile<128, 512>(V + m0 * 2048 + 64, 2048, Ab[1], tid);
  dma_tile<128, 512>(W + n0 * 2048 + 64, 2048, Bb[1], tid);

  // ---- main loop: 32 K-steps, counted vmcnt, 2 raw barriers/step ----
  #pragma unroll 1
  for(int t = 0; t < 32; ++t){
    if(t < 31){ asm volatile("s_waitcnt vmcnt(4)" ::: "memory"); }
    else      { asm volatile("s_waitcnt vmcnt(0)" ::: "memory"); }
    __builtin_amdgcn_sched_barrier(0);
    __builtin_amdgcn_s_barrier();               // B1: tile t visible to all
    __builtin_amdgcn_sched_barrier(0);
    mfma_on(Ab[t & 1], Bb[t & 1], accW);
    asm volatile("s_waitcnt lgkmcnt(0)" ::: "memory");
    __builtin_amdgcn_sched_barrier(0);
    __builtin_amdgcn_s_barrier();               // B2: all waves done reading buf
    __builtin_amdgcn_sched_barrier(0);
    if(t + 2 < 32){
      dma_tile<128, 512>(V + m0 * 2048 + (t + 2) * 64, 2048, Ab[t & 1], tid);
      dma_tile<128, 512>(W + n0 * 2048 + (t + 2) * 64, 2048, Bb[t & 1], tid);
    }
  }
  __syncthreads();

  if(role == 0){
    // g1 = xh * zx
    #pragma unroll
    for(int j = 0; j < 4; ++j){
      int n = n0 + wc * 64 + j * 16 + (lane & 15);
      #pragma unroll
      for(int i = 0; i < 2; ++i){
        #pragma unroll
        for(int r = 0; r < 4; ++r){
          int m = m0 + wr * 32 + i * 16 + (lane >> 4) * 4 + r;
          g1[m * 8192 + n] = f2bf(accW[i][j][r] * accZ[i][j][r]);
        }
      }
    }
  } else {
    // accW = hh * zh; zb mini into accZ; g2 = accW + zb + bias
    #pragma unroll
    for(int i = 0; i < 2; ++i)
      #pragma unroll
      for(int j = 0; j < 4; ++j)
        #pragma unroll
        for(int r = 0; r < 4; ++r)
          accW[i][j][r] *= accZ[i][j][r];
    zero(accZ);
    stage_tile<128, 512>(P + m0 * 768 + 512 + g * 64, 768, Ab[0], tid);
    stage_tile<128, 512>(Wsb + (g * 2048 + hc0) * 64, 64, Bb[0], tid);
    __syncthreads();
    mfma_on(Ab[0], Bb[0], accZ);
    #pragma unroll
    for(int j = 0; j < 4; ++j){
      int n = n0 + wc * 64 + j * 16 + (lane & 15);
      float bv = bias[n];
      #pragma unroll
      for(int i = 0; i < 2; ++i){
        #pragma unroll
        for(int r = 0; r < 4; ++r){
          int m = m0 + wr * 32 + i * 16 + (lane >> 4) * 4 + r;
          g2[m * 8192 + n] = f2bf(accW[i][j][r] + accZ[i][j][r] + bv);
        }
      }
    }
  }
}

// ---------- reg-staged fallback (round-9 proven path) ----------
template<int NROWS>
struct Stage {
  float4 v[(NROWS * 16) / 256];
  __device__ __forceinline__ void load(const float* __restrict__ src, int stride, int tid){
    #pragma unroll
    for(int s = 0; s < (NROWS * 16) / 256; ++s){
      int fi = tid + s * 256;
      v[s] = *(reinterpret_cast<const float4*>(src + (fi >> 4) * stride) + (fi & 15));
    }
  }
  __device__ __forceinline__ void write(unsigned short* lds, int tid){
    #pragma unroll
    for(int s = 0; s < (NROWS * 16) / 256; ++s){
      int fi = tid + s * 256;
      int row = fi >> 4, kf = fi & 15;
      unsigned int lo = pk_bf16(v[s].x, v[s].y), hi = pk_bf16(v[s].z, v[s].w);
      int byte = ((row << 7) + (kf << 3)) ^ ((row & 7) << 4);
      uint2 u; u.x = lo; u.y = hi;
      *reinterpret_cast<uint2*>(reinterpret_cast<char*>(lds) + byte) = u;
    }
  }
};

__global__ __launch_bounds__(256, 2) void k4_gates_reg(
    const float* __restrict__ x, const float* __restrict__ h,
    const float* __restrict__ Wih, const float* __restrict__ Whh,
    const float* __restrict__ bias, const float* __restrict__ P,
    const float* __restrict__ Wsh, const float* __restrict__ Wsx,
    const float* __restrict__ Wsb,
    unsigned short* __restrict__ g1, unsigned short* __restrict__ g2){
  __shared__ unsigned short Ab[2][64 * 64];
  __shared__ unsigned short Bb[2][128 * 64];
  int tid = threadIdx.x, lane = tid & 63, w = tid >> 6;
  int wr = w >> 1, wc = w & 1;
  int fid = blockIdx.x;
  int role = fid >> 9;
  int rid = fid & 511;
  int xcd = rid & 7, idx = rid >> 3;
  int nt = xcd * 8 + (idx >> 3);
  int mt = idx & 7;
  int n0 = nt << 7, m0 = mt << 6;
  int g = n0 >> 11, hc0 = n0 & 2047;

  const float* V  = role ? h : x;
  const float* W  = role ? Whh : Wih;
  const float* Pm = P + m0 * 768 + (role ? 0 : 256) + g * 64;
  const float* Ws = (role ? Wsh : Wsx) + (g * 2048 + hc0) * 64;

  f32x4 accZ[2][4], accW[2][4];
  Stage<64>  LA;
  Stage<128> LB;

  auto zero = [&](f32x4 (&a)[2][4]){
    const f32x4 zf = {0.f, 0.f, 0.f, 0.f};
    #pragma unroll
    for(int i = 0; i < 2; ++i)
      #pragma unroll
      for(int j = 0; j < 4; ++j) a[i][j] = zf;
  };
  auto mfma_on = [&](const unsigned short* A_, const unsigned short* B_, f32x4 (&acc)[2][4]){
    #pragma unroll
    for(int ks = 0; ks < 64; ks += 32){
      bf16x8 af[2], bfr[4];
      #pragma unroll
      for(int i = 0; i < 2; ++i) af[i]  = read_frag(A_, wr * 32 + i * 16 + (lane & 15), ks, lane);
      #pragma unroll
      for(int j = 0; j < 4; ++j) bfr[j] = read_frag(B_, wc * 64 + j * 16 + (lane & 15), ks, lane);
      #pragma unroll
      for(int i = 0; i < 2; ++i){
        #pragma unroll
        for(int j = 0; j < 4; ++j)
          acc[i][j] = __builtin_amdgcn_mfma_f32_16x16x32_bf16(af[i], bfr[j], acc[i][j], 0, 0, 0);
      }
    }
  };

  zero(accZ); zero(accW);
  stage_tile<64, 256>(Pm, 768, Ab[0], tid);
  stage_tile<128, 256>(Ws, 64, Bb[0], tid);
  LA.load(V + m0 * 2048, 2048, tid);
  LB.load(W + n0 * 2048, 2048, tid);
  __syncthreads();
  mfma_on(Ab[0], Bb[0], accZ);
  __syncthreads();
  LA.write(Ab[0], tid); LB.write(Bb[0], tid);
  LA.load(V + m0 * 2048 + 64, 2048, tid);
  LB.load(W + n0 * 2048 + 64, 2048, tid);
  __syncthreads();

  #pragma unroll 1
  for(int t = 0; t < 32; ++t){
    if(t + 1 < 32){
      LA.write(Ab[(t + 1) & 1], tid);
      LB.write(Bb[(t + 1) & 1], tid);
      if(t + 2 < 32){
        LA.load(V + m0 * 2048 + (t + 2) * 64, 2048, tid);
        LB.load(W + n0 * 2048 + (t + 2) * 64, 2048, tid);
      }
    }
    mfma_on(Ab[t & 1], Bb[t & 1], accW);
    __syncthreads();
  }

  if(role == 0){
    #pragma unroll
    for(int j = 0; j < 4; ++j){
      int n = n0 + wc * 64 + j * 16 + (lane & 15);
      #pragma unroll
      for(int i = 0; i < 2; ++i){
        #pragma unroll
        for(int r = 0; r < 4; ++r){
          int m = m0 + wr * 32 + i * 16 + (lane >> 4) * 4 + r;
          g1[m * 8192 + n] = f2bf(accW[i][j][r] * accZ[i][j][r]);
        }
      }
    }
  } else {
    #pragma unroll
    for(int i = 0; i < 2; ++i)
      #pragma unroll
      for(int j = 0; j < 4; ++j)
        #pragma unroll
        for(int r = 0; r < 4; ++r)
          accW[i][j][r] *= accZ[i][j][r];
    zero(accZ);
    stage_tile<64, 256>(P + m0 * 768 + 512 + g * 64, 768, Ab[0], tid);
    stage_tile<128, 256>(Wsb + (g * 2048 + hc0) * 64, 64, Bb[0], tid);
    __syncthreads();
    mfma_on(Ab[0], Bb[0], accZ);
    #pragma unroll
    for(int j = 0; j < 4; ++j){
      int n = n0 + wc * 64 + j * 16 + (lane & 15);
      float bv = bias[n];
      #pragma unroll
      for(int i = 0; i < 2; ++i){
        #pragma unroll
        for(int r = 0; r < 4; ++r){
          int m = m0 + wr * 32 + i * 16 + (lane >> 4) * 4 + r;
          g2[m * 8192 + n] = f2bf(accW[i][j][r] + accZ[i][j][r] + bv);
        }
      }
    }
  }
}

// =====================================================================
// K5: gates = g1 + g2 (bf16 halves), gate LN + LSTM cell + c-LN.
// =====================================================================
__global__ __launch_bounds__(256) void k5_cell(
    const unsigned short* __restrict__ g1, const unsigned short* __restrict__ g2,
    const float* __restrict__ c,
    const float* __restrict__ lng, const float* __restrict__ lnb,
    const float* __restrict__ lncg, const float* __restrict__ lncb,
    float* __restrict__ out){
  __shared__ float G[4 * 2048];
  __shared__ float red[4];
  int tid = threadIdx.x, lane = tid & 63, w = tid >> 6;
  int b = blockIdx.x;
  const unsigned short* r1 = g1 + b * 8192 + w * 2048 + lane * 32;
  const unsigned short* r2 = g2 + b * 8192 + w * 2048 + lane * 32;
  float gv[32]; float s = 0.f;
  #pragma unroll
  for(int t = 0; t < 4; ++t){
    uint4 a  = *reinterpret_cast<const uint4*>(r1 + t * 8);
    uint4 bb = *reinterpret_cast<const uint4*>(r2 + t * 8);
    unsigned int aw[4] = {a.x, a.y, a.z, a.w};
    unsigned int bw[4] = {bb.x, bb.y, bb.z, bb.w};
    #pragma unroll
    for(int k = 0; k < 4; ++k){
      float f0 = bfu(aw[k] & 0xffffu) + bfu(bw[k] & 0xffffu);
      float f1 = bfu(aw[k] >> 16)     + bfu(bw[k] >> 16);
      gv[t * 8 + 2 * k]     = f0;
      gv[t * 8 + 2 * k + 1] = f1;
      s += f0 + f1;
    }
  }
  float mean = wave_sum(s) * (1.f / 2048.f);
  float sse = 0.f;
  #pragma unroll
  for(int q = 0; q < 32; ++q){ float d = gv[q] - mean; sse += d * d; }
  float inv = 1.f / (sqrtf(wave_sum(sse) * (1.f / 2047.f)) + LN_EPS);
  #pragma unroll
  for(int q = 0; q < 32; ++q){
    int e = w * 2048 + lane * 32 + q;
    G[e] = lng[e] * (gv[q] - mean) * inv + lnb[e];
  }
  __syncthreads();
  float nc[8], os[8], s2 = 0.f;
  #pragma unroll
  for(int q = 0; q < 8; ++q){
    int e = tid + 256 * q;
    float iv = G[e], fv = G[2048 + e], gg = G[4096 + e], ov = G[6144 + e];
    float cc = c[b * 2048 + e];
    nc[q] = cc * sigf(fv) + sigf(iv) * tanh_f(gg);
    os[q] = sigf(ov);
    s2 += nc[q];
  }
  s2 = wave_sum(s2);
  if(lane == 0) red[w] = s2;
  __syncthreads();
  float mean2 = (red[0] + red[1] + red[2] + red[3]) * (1.f / 2048.f);
  float sse2 = 0.f;
  #pragma unroll
  for(int q = 0; q < 8; ++q){ float d = nc[q] - mean2; sse2 += d * d; }
  sse2 = wave_sum(sse2);
  __syncthreads();
  if(lane == 0) red[w] = sse2;
  __syncthreads();
  float inv2 = 1.f / (sqrtf((red[0] + red[1] + red[2] + red[3]) * (1.f / 2047.f)) + LN_EPS);
  #pragma unroll
  for(int q = 0; q < 8; ++q){
    int e = tid + 256 * q;
    float ncn = lncg[e] * (nc[q] - mean2) * inv2 + lncb[e];
    out[b * 2048 + e]           = tanh_f(ncn) * os[q];  // new_h
    out[1048576 + b * 2048 + e] = ncn;                  // new_c
  }
}

// =====================================================================
extern "C" void kernel_launch(void* const* d_in, const int* in_sizes, int n_in,
                              void* d_out, int out_size, void* d_ws, size_t ws_size,
                              hipStream_t stream){
  const float* x        = (const float*)d_in[0];
  const float* h        = (const float*)d_in[1];
  const float* c        = (const float*)d_in[2];
  const float* hyper_h  = (const float*)d_in[3];
  const float* hyper_c  = (const float*)d_in[4];
  const float* hc_Wih   = (const float*)d_in[5];
  const float* hc_bih   = (const float*)d_in[6];
  const float* hc_Whh   = (const float*)d_in[7];
  const float* hc_lng   = (const float*)d_in[8];
  const float* hc_lnb   = (const float*)d_in[9];
  const float* hc_lncg  = (const float*)d_in[10];
  const float* hc_lncb  = (const float*)d_in[11];
  const float* Wph      = (const float*)d_in[12];
  const float* bph      = (const float*)d_in[13];
  const float* Wpx      = (const float*)d_in[14];
  const float* bpx      = (const float*)d_in[15];
  const float* Wpb      = (const float*)d_in[16];
  const float* Wsh      = (const float*)d_in[17];
  const float* Wsx      = (const float*)d_in[18];
  const float* Wsb      = (const float*)d_in[19];
  const float* Wih      = (const float*)d_in[20];
  const float* Whh      = (const float*)d_in[21];
  const float* bias     = (const float*)d_in[22];
  const float* ln_g     = (const float*)d_in[23];
  const float* ln_b     = (const float*)d_in[24];
  const float* lnc_g    = (const float*)d_in[25];
  const float* lnc_b    = (const float*)d_in[26];

  float* out = (float*)d_out;
  // ws: v1 1MB | v2 1MB | P 1.5MB | g1 8.4MB | g2 8.4MB | bf16 pool [Wih 33.5 | Whh 33.5 | x 2 | h 2]
  unsigned short* ws_v1 = (unsigned short*)d_ws;            // 512*1024
  unsigned short* ws_v2 = ws_v1 + 524288;                   // 512*1024
  float*          ws_P  = (float*)(ws_v2 + 524288);         // 512*768
  unsigned short* ws_g1 = (unsigned short*)(ws_P + 393216); // 512*8192
  unsigned short* ws_g2 = ws_g1 + 4194304;                  // 512*8192
  unsigned short* ws_bf = ws_g2 + 4194304;                  // bf16 pool
  unsigned short* Wihbf = ws_bf;                            // 16777216 elems
  unsigned short* Whhbf = Wihbf + 16777216;
  unsigned short* xbf   = Whhbf + 16777216;                 // 1048576
  unsigned short* hbf   = xbf + 1048576;
  const size_t WS_NEED = 91750400;                          // bytes
  const float* nhh = out + 2097152;

  bool dma = (ws_size >= WS_NEED);

  if(dma)
    kconv<<<2176, 256, 0, stream>>>(Wih, Whh, x, h, ws_bf);
  k1_hyper_gemm<<<1024, 256, 0, stream>>>(x, h, hyper_h, hc_Wih, hc_Whh, ws_v1, ws_v2);
  k2_hyper_cell<<<128, 256, 0, stream>>>(ws_v1, ws_v2, hc_bih, hyper_c, hc_lng, hc_lnb, hc_lncg, hc_lncb, out);
  k3_pmat<<<dim3(12, 8), 256, 0, stream>>>(nhh, Wph, Wpx, Wpb, bph, bpx, ws_P);
  if(dma)
    k4_gates_dma<<<512, 512, 0, stream>>>(xbf, hbf, Wihbf, Whhbf, bias, ws_P, Wsh, Wsx, Wsb, ws_g1, ws_g2);
  else
    k4_gates_reg<<<1024, 256, 0, stream>>>(x, h, Wih, Whh, bias, ws_P, Wsh, Wsx, Wsb, ws_g1, ws_g2);
  k5_cell<<<512, 256, 0, stream>>>(ws_g1, ws_g2, c, ln_g, ln_b, lnc_g, lnc_b, out);
}

// Round 14
// 121.210 us; speedup vs baseline: 1.3512x; 1.3512x over previous
//
#include <hip/hip_runtime.h>
#include <hip/hip_bf16.h>
#include <math.h>

typedef __attribute__((ext_vector_type(4))) float  f32x4;
typedef __attribute__((ext_vector_type(8))) __bf16 bf16x8;

#define LN_EPS 1e-6f

// ---------- small math helpers ----------
__device__ __forceinline__ float sigf(float v){ return 1.f / (1.f + __expf(-v)); }
__device__ __forceinline__ float tanh_f(float v){
  float t = __expf(-2.f * fabsf(v));
  float r = (1.f - t) / (1.f + t);
  return copysignf(r, v);
}
__device__ __forceinline__ float wave_sum(float v){
  #pragma unroll
  for(int m = 1; m < 64; m <<= 1) v += __shfl_xor(v, m, 64);
  return v;
}

// f32 -> bf16 via hardware cvt (RNE); pairs fuse into v_cvt_pk_bf16_f32
__device__ __forceinline__ unsigned short f2bf(float f){
  return __builtin_bit_cast(unsigned short, static_cast<__bf16>(f));
}
__device__ __forceinline__ unsigned int pk_bf16(float a, float b){
  return (unsigned int)f2bf(a) | ((unsigned int)f2bf(b) << 16);
}
__device__ __forceinline__ float bfu(unsigned int u){  // low 16 bits = bf16
  unsigned int t = u << 16;
  return __builtin_bit_cast(float, t);
}

// ---------- fused reg staging (load f32 + cvt + swizzled ds_write) ----------
// LDS layout: row-major [NROWS][64] bf16 (128 B/row), byte ^= (row&7)<<4
template<int NROWS, int NTHR>
__device__ __forceinline__ void stage_tile(const float* __restrict__ src, int row_stride,
                                           unsigned short* lds, int tid){
  constexpr int PER = (NROWS * 16) / NTHR;   // float4's per thread
  #pragma unroll
  for(int s = 0; s < PER; ++s){
    int fi  = tid + s * NTHR;
    int row = fi >> 4, kf = fi & 15;
    float4 v = *(reinterpret_cast<const float4*>(src + row * row_stride) + kf);
    unsigned int lo = pk_bf16(v.x, v.y), hi = pk_bf16(v.z, v.w);
    int byte = ((row << 7) + (kf << 3)) ^ ((row & 7) << 4);
    uint2 u; u.x = lo; u.y = hi;
    *reinterpret_cast<uint2*>(reinterpret_cast<char*>(lds) + byte) = u;
  }
}

// ---------- split staging with landing regs (loads stay in flight) ----------
template<int NROWS, int NTHR>
struct StageF {
  float4 v[(NROWS * 16) / NTHR];
  __device__ __forceinline__ void load(const float* __restrict__ src, int stride, int tid){
    #pragma unroll
    for(int s = 0; s < (NROWS * 16) / NTHR; ++s){
      int fi = tid + s * NTHR;
      v[s] = *(reinterpret_cast<const float4*>(src + (fi >> 4) * stride) + (fi & 15));
    }
  }
  __device__ __forceinline__ void write(unsigned short* lds, int tid){
    #pragma unroll
    for(int s = 0; s < (NROWS * 16) / NTHR; ++s){
      int fi = tid + s * NTHR;
      int row = fi >> 4, kf = fi & 15;
      unsigned int lo = pk_bf16(v[s].x, v[s].y), hi = pk_bf16(v[s].z, v[s].w);
      int byte = ((row << 7) + (kf << 3)) ^ ((row & 7) << 4);
      uint2 u; u.x = lo; u.y = hi;
      *reinterpret_cast<uint2*>(reinterpret_cast<char*>(lds) + byte) = u;
    }
  }
};

// read one 16x32 MFMA operand fragment (swizzled layout)
__device__ __forceinline__ bf16x8 read_frag(const unsigned short* lds, int row, int ks, int lane){
  int byte = ((row << 7) + ((ks + ((lane >> 4) << 3)) << 1)) ^ ((row & 7) << 4);
  return *reinterpret_cast<const bf16x8*>(reinterpret_cast<const char*>(lds) + byte);
}

// =====================================================================
// K1: v = [x | h | hyper_h] @ [hc_Wih | hc_Whh]^T   (512 x 1024, K=4352)
// K split in 2 halves across block roles -> 1024 blocks; bf16 halves to v1/v2.
// =====================================================================
__global__ __launch_bounds__(256, 2) void k1_hyper_gemm(
    const float* __restrict__ x, const float* __restrict__ h,
    const float* __restrict__ hyper_h, const float* __restrict__ hc_Wih,
    const float* __restrict__ hc_Whh,
    unsigned short* __restrict__ v1, unsigned short* __restrict__ v2){
  __shared__ unsigned short Ab[32 * 64];
  __shared__ unsigned short Bb[32 * 64];
  int tid = threadIdx.x, lane = tid & 63, w = tid >> 6;
  int wr = w >> 1, wc = w & 1;
  int fid = blockIdx.x;
  int half = fid >> 9, rid = fid & 511;
  int n0 = (rid & 31) * 32, m0 = (rid >> 5) * 32;
  unsigned short* vo = half ? v2 : v1;
  int kb = half * 2176;
  f32x4 acc = {0.f, 0.f, 0.f, 0.f};

  #pragma unroll 1
  for(int kk = 0; kk < 2176; kk += 64){
    int k0 = kb + kk;
    const float* as; int ast;
    if(k0 < 2048)      { as = x       + m0 * 2048 + k0;          ast = 2048; }
    else if(k0 < 4096) { as = h       + m0 * 2048 + (k0 - 2048); ast = 2048; }
    else               { as = hyper_h + m0 * 256  + (k0 - 4096); ast = 256;  }
    const float* bs; int bst;
    if(k0 < 4096)      { bs = hc_Wih  + n0 * 4096 + k0;          bst = 4096; }
    else               { bs = hc_Whh  + n0 * 256  + (k0 - 4096); bst = 256;  }
    __syncthreads();
    stage_tile<32, 256>(as, ast, Ab, tid);
    stage_tile<32, 256>(bs, bst, Bb, tid);
    __syncthreads();
    #pragma unroll
    for(int ks = 0; ks < 64; ks += 32){
      bf16x8 af = read_frag(Ab, wr * 16 + (lane & 15), ks, lane);
      bf16x8 bf = read_frag(Bb, wc * 16 + (lane & 15), ks, lane);
      acc = __builtin_amdgcn_mfma_f32_16x16x32_bf16(af, bf, acc, 0, 0, 0);
    }
  }
  int n = n0 + wc * 16 + (lane & 15);
  #pragma unroll
  for(int r = 0; r < 4; ++r){
    int m = m0 + wr * 16 + (lane >> 4) * 4 + r;
    vo[m * 1024 + n] = f2bf(acc[r]);
  }
}

// =====================================================================
// K2: v = v1 + v2 + hc_bih, hyper LN + hyper LSTM cell. 1 wave per row.
// =====================================================================
__global__ __launch_bounds__(256) void k2_hyper_cell(
    const unsigned short* __restrict__ v1, const unsigned short* __restrict__ v2,
    const float* __restrict__ bih, const float* __restrict__ hyper_c,
    const float* __restrict__ lng, const float* __restrict__ lnb,
    const float* __restrict__ lncg, const float* __restrict__ lncb,
    float* __restrict__ out){
  int tid = threadIdx.x, lane = tid & 63, w = tid >> 6;
  int b = blockIdx.x * 4 + w;
  float vn[4][4];
  #pragma unroll
  for(int g = 0; g < 4; ++g){
    float vv[4], s = 0.f;
    #pragma unroll
    for(int q = 0; q < 4; ++q){
      int e = lane + 64 * q;
      int bi = b * 1024 + g * 256 + e;
      vv[q] = bfu(v1[bi]) + bfu(v2[bi]) + bih[g * 256 + e];
      s += vv[q];
    }
    float mean = wave_sum(s) * (1.f / 256.f);
    float sse = 0.f;
    #pragma unroll
    for(int q = 0; q < 4; ++q){ float d = vv[q] - mean; sse += d * d; }
    float inv = 1.f / (sqrtf(wave_sum(sse) * (1.f / 255.f)) + LN_EPS);
    #pragma unroll
    for(int q = 0; q < 4; ++q){
      int e = lane + 64 * q;
      vn[g][q] = lng[g * 256 + e] * (vv[q] - mean) * inv + lnb[g * 256 + e];
    }
  }
  float ncr[4], os[4], s2 = 0.f;
  #pragma unroll
  for(int q = 0; q < 4; ++q){
    float hc = hyper_c[b * 256 + lane + 64 * q];
    float hi = vn[0][q], hf = vn[1][q] + 1.f, hg = vn[2][q], ho = vn[3][q];
    ncr[q] = hc * sigf(hf) + sigf(hi) * tanh_f(hg);
    os[q]  = sigf(ho);
    s2 += ncr[q];
  }
  float mean2 = wave_sum(s2) * (1.f / 256.f);
  float sse2 = 0.f;
  #pragma unroll
  for(int q = 0; q < 4; ++q){ float d = ncr[q] - mean2; sse2 += d * d; }
  float inv2 = 1.f / (sqrtf(wave_sum(sse2) * (1.f / 255.f)) + LN_EPS);
  #pragma unroll
  for(int q = 0; q < 4; ++q){
    int e = lane + 64 * q;
    float ncn = lncg[e] * (ncr[q] - mean2) * inv2 + lncb[e];
    out[2097152 + b * 256 + e] = tanh_f(ncn) * os[q];  // new_hyper_h
    out[2228224 + b * 256 + e] = ncn;                  // new_hyper_c
  }
}

// =====================================================================
// K3: P = nhh @ [Wph|Wpx|Wpb]^T + [bph|bpx|0]   (512 x 768, K=256)
// =====================================================================
__global__ __launch_bounds__(256, 2) void k3_pmat(
    const float* __restrict__ nhh, const float* __restrict__ Wph,
    const float* __restrict__ Wpx, const float* __restrict__ Wpb,
    const float* __restrict__ bph, const float* __restrict__ bpx,
    float* __restrict__ P){
  __shared__ unsigned short Ab[64 * 64];
  __shared__ unsigned short Bb[64 * 64];
  int tid = threadIdx.x, lane = tid & 63, w = tid >> 6;
  int wr = w >> 1, wc = w & 1;
  int n0 = blockIdx.x * 64, m0 = blockIdx.y * 64;
  int j3 = n0 >> 8, jr0 = n0 & 255;
  const float* W = (j3 == 0) ? Wph : (j3 == 1) ? Wpx : Wpb;
  f32x4 acc[2][2];
  const f32x4 zf = {0.f, 0.f, 0.f, 0.f};
  #pragma unroll
  for(int i = 0; i < 2; ++i){ acc[i][0] = zf; acc[i][1] = zf; }

  #pragma unroll 1
  for(int k0 = 0; k0 < 256; k0 += 64){
    __syncthreads();
    stage_tile<64, 256>(nhh + m0 * 256 + k0, 256, Ab, tid);
    stage_tile<64, 256>(W + jr0 * 256 + k0, 256, Bb, tid);
    __syncthreads();
    #pragma unroll
    for(int ks = 0; ks < 64; ks += 32){
      bf16x8 af[2], bfr[2];
      #pragma unroll
      for(int i = 0; i < 2; ++i) af[i]  = read_frag(Ab, wr * 32 + i * 16 + (lane & 15), ks, lane);
      #pragma unroll
      for(int j = 0; j < 2; ++j) bfr[j] = read_frag(Bb, wc * 32 + j * 16 + (lane & 15), ks, lane);
      #pragma unroll
      for(int i = 0; i < 2; ++i){
        #pragma unroll
        for(int j = 0; j < 2; ++j)
          acc[i][j] = __builtin_amdgcn_mfma_f32_16x16x32_bf16(af[i], bfr[j], acc[i][j], 0, 0, 0);
      }
    }
  }
  #pragma unroll
  for(int j = 0; j < 2; ++j){
    int cj = jr0 + wc * 32 + j * 16 + (lane & 15);
    float bv = (j3 == 0) ? bph[cj] : (j3 == 1) ? bpx[cj] : 0.f;
    int n = n0 + wc * 32 + j * 16 + (lane & 15);
    #pragma unroll
    for(int i = 0; i < 2; ++i){
      #pragma unroll
      for(int r = 0; r < 4; ++r){
        int m = m0 + wr * 32 + i * 16 + (lane >> 4) * 4 + r;
        P[m * 768 + n] = acc[i][j][r] + bv;
      }
    }
  }
}

// =====================================================================
// K4: reg-staged, role-split, 512 blocks x 512 thr (EXACTLY 2 blocks/CU,
// no tail), 128x128 tile, 8 waves (4x2, wave tile 32x64), BK=64,
// double-buffered 64 KB LDS, r9-proven pipeline:
//   per step: { write tile t+1 from landing regs; issue loads t+2;
//               MFMA tile t; barrier }
// Per-thread staging: 8 loads + 16 cvt + 8 ds_writes (half of r9's).
//   role X: g1 = bf16( (x@Wih^T) * zx );  role H: g2 = bf16( (h@Whh^T)*zh + zb + bias )
// launch_bounds(512,2): no VGPR squeeze (the (_,4) trap is proven).
// =====================================================================
__global__ __launch_bounds__(512, 2) void k4_gates(
    const float* __restrict__ x, const float* __restrict__ h,
    const float* __restrict__ Wih, const float* __restrict__ Whh,
    const float* __restrict__ bias, const float* __restrict__ P,
    const float* __restrict__ Wsh, const float* __restrict__ Wsx,
    const float* __restrict__ Wsb,
    unsigned short* __restrict__ g1, unsigned short* __restrict__ g2){
  __shared__ unsigned short Ab[2][128 * 64];   // 2 x 16 KB
  __shared__ unsigned short Bb[2][128 * 64];   // 2 x 16 KB
  int tid = threadIdx.x, lane = tid & 63, w = tid >> 6;
  int wr = w >> 1, wc = w & 1;                 // 4x2 wave grid, wave tile 32x64
  int fid = blockIdx.x;                        // 512 blocks
  int role = fid >> 8;
  int rid = fid & 255;
  int xcd = rid & 7, idx = rid >> 3;           // idx 0..31
  int nt = xcd * 8 + (idx >> 2);               // n-tile 0..63 (8 per XCD)
  int mt = idx & 3;                            // m-tile 0..3 (128 rows each)
  int n0 = nt << 7, m0 = mt << 7;
  int g = n0 >> 11, hc0 = n0 & 2047;

  const float* V  = role ? h : x;
  const float* W  = role ? Whh : Wih;
  const float* Pm = P + m0 * 768 + (role ? 0 : 256) + g * 64;
  const float* Ws = (role ? Wsh : Wsx) + (g * 2048 + hc0) * 64;

  f32x4 accZ[2][4], accW[2][4];
  StageF<128, 512> LA;     // 4 float4 landing regs
  StageF<128, 512> LB;     // 4 float4 landing regs

  auto zero = [&](f32x4 (&a)[2][4]){
    const f32x4 zf = {0.f, 0.f, 0.f, 0.f};
    #pragma unroll
    for(int i = 0; i < 2; ++i)
      #pragma unroll
      for(int j = 0; j < 4; ++j) a[i][j] = zf;
  };
  auto mfma_on = [&](const unsigned short* A_, const unsigned short* B_, f32x4 (&acc)[2][4]){
    #pragma unroll
    for(int ks = 0; ks < 64; ks += 32){
      bf16x8 af[2], bfr[4];
      #pragma unroll
      for(int i = 0; i < 2; ++i) af[i]  = read_frag(A_, wr * 32 + i * 16 + (lane & 15), ks, lane);
      #pragma unroll
      for(int j = 0; j < 4; ++j) bfr[j] = read_frag(B_, wc * 64 + j * 16 + (lane & 15), ks, lane);
      #pragma unroll
      for(int i = 0; i < 2; ++i){
        #pragma unroll
        for(int j = 0; j < 4; ++j)
          acc[i][j] = __builtin_amdgcn_mfma_f32_16x16x32_bf16(af[i], bfr[j], acc[i][j], 0, 0, 0);
      }
    }
  };

  zero(accZ); zero(accW);

  // ---- prologue: z mini-GEMM in buf0, then prefetch W-loop tiles 0 and 1 ----
  stage_tile<128, 512>(Pm, 768, Ab[0], tid);
  stage_tile<128, 512>(Ws, 64, Bb[0], tid);
  LA.load(V + m0 * 2048, 2048, tid);            // tile 0
  LB.load(W + n0 * 2048, 2048, tid);
  __syncthreads();
  mfma_on(Ab[0], Bb[0], accZ);                  // z tile
  __syncthreads();                              // buf0 free
  LA.write(Ab[0], tid); LB.write(Bb[0], tid);   // tile 0 -> buf0 (vmcnt waits)
  LA.load(V + m0 * 2048 + 64, 2048, tid);       // tile 1
  LB.load(W + n0 * 2048 + 64, 2048, tid);
  __syncthreads();                              // tile 0 visible

  // ---- main loop: 32 K-steps, one barrier each ----
  #pragma unroll 1
  for(int t = 0; t < 32; ++t){
    if(t + 1 < 32){
      LA.write(Ab[(t + 1) & 1], tid);           // tile t+1 (WAR ok: last read t-1)
      LB.write(Bb[(t + 1) & 1], tid);
      if(t + 2 < 32){
        LA.load(V + m0 * 2048 + (t + 2) * 64, 2048, tid);
        LB.load(W + n0 * 2048 + (t + 2) * 64, 2048, tid);
      }
    }
    mfma_on(Ab[t & 1], Bb[t & 1], accW);        // tile t (RAW ok: barrier t-1)
    __syncthreads();
  }

  if(role == 0){
    // g1 = xh * zx
    #pragma unroll
    for(int j = 0; j < 4; ++j){
      int n = n0 + wc * 64 + j * 16 + (lane & 15);
      #pragma unroll
      for(int i = 0; i < 2; ++i){
        #pragma unroll
        for(int r = 0; r < 4; ++r){
          int m = m0 + wr * 32 + i * 16 + (lane >> 4) * 4 + r;
          g1[m * 8192 + n] = f2bf(accW[i][j][r] * accZ[i][j][r]);
        }
      }
    }
  } else {
    // accW = hh * zh; zb mini into accZ; g2 = accW + zb + bias
    #pragma unroll
    for(int i = 0; i < 2; ++i)
      #pragma unroll
      for(int j = 0; j < 4; ++j)
        #pragma unroll
        for(int r = 0; r < 4; ++r)
          accW[i][j][r] *= accZ[i][j][r];
    zero(accZ);
    stage_tile<128, 512>(P + m0 * 768 + 512 + g * 64, 768, Ab[0], tid);
    stage_tile<128, 512>(Wsb + (g * 2048 + hc0) * 64, 64, Bb[0], tid);
    __syncthreads();
    mfma_on(Ab[0], Bb[0], accZ);
    #pragma unroll
    for(int j = 0; j < 4; ++j){
      int n = n0 + wc * 64 + j * 16 + (lane & 15);
      float bv = bias[n];
      #pragma unroll
      for(int i = 0; i < 2; ++i){
        #pragma unroll
        for(int r = 0; r < 4; ++r){
          int m = m0 + wr * 32 + i * 16 + (lane >> 4) * 4 + r;
          g2[m * 8192 + n] = f2bf(accW[i][j][r] + accZ[i][j][r] + bv);
        }
      }
    }
  }
}

// =====================================================================
// K5: gates = g1 + g2 (bf16 halves), gate LN + LSTM cell + c-LN.
// =====================================================================
__global__ __launch_bounds__(256) void k5_cell(
    const unsigned short* __restrict__ g1, const unsigned short* __restrict__ g2,
    const float* __restrict__ c,
    const float* __restrict__ lng, const float* __restrict__ lnb,
    const float* __restrict__ lncg, const float* __restrict__ lncb,
    float* __restrict__ out){
  __shared__ float G[4 * 2048];
  __shared__ float red[4];
  int tid = threadIdx.x, lane = tid & 63, w = tid >> 6;
  int b = blockIdx.x;
  const unsigned short* r1 = g1 + b * 8192 + w * 2048 + lane * 32;
  const unsigned short* r2 = g2 + b * 8192 + w * 2048 + lane * 32;
  float gv[32]; float s = 0.f;
  #pragma unroll
  for(int t = 0; t < 4; ++t){
    uint4 a  = *reinterpret_cast<const uint4*>(r1 + t * 8);
    uint4 bb = *reinterpret_cast<const uint4*>(r2 + t * 8);
    unsigned int aw[4] = {a.x, a.y, a.z, a.w};
    unsigned int bw[4] = {bb.x, bb.y, bb.z, bb.w};
    #pragma unroll
    for(int k = 0; k < 4; ++k){
      float f0 = bfu(aw[k] & 0xffffu) + bfu(bw[k] & 0xffffu);
      float f1 = bfu(aw[k] >> 16)     + bfu(bw[k] >> 16);
      gv[t * 8 + 2 * k]     = f0;
      gv[t * 8 + 2 * k + 1] = f1;
      s += f0 + f1;
    }
  }
  float mean = wave_sum(s) * (1.f / 2048.f);
  float sse = 0.f;
  #pragma unroll
  for(int q = 0; q < 32; ++q){ float d = gv[q] - mean; sse += d * d; }
  float inv = 1.f / (sqrtf(wave_sum(sse) * (1.f / 2047.f)) + LN_EPS);
  #pragma unroll
  for(int q = 0; q < 32; ++q){
    int e = w * 2048 + lane * 32 + q;
    G[e] = lng[e] * (gv[q] - mean) * inv + lnb[e];
  }
  __syncthreads();
  float nc[8], os[8], s2 = 0.f;
  #pragma unroll
  for(int q = 0; q < 8; ++q){
    int e = tid + 256 * q;
    float iv = G[e], fv = G[2048 + e], gg = G[4096 + e], ov = G[6144 + e];
    float cc = c[b * 2048 + e];
    nc[q] = cc * sigf(fv) + sigf(iv) * tanh_f(gg);
    os[q] = sigf(ov);
    s2 += nc[q];
  }
  s2 = wave_sum(s2);
  if(lane == 0) red[w] = s2;
  __syncthreads();
  float mean2 = (red[0] + red[1] + red[2] + red[3]) * (1.f / 2048.f);
  float sse2 = 0.f;
  #pragma unroll
  for(int q = 0; q < 8; ++q){ float d = nc[q] - mean2; sse2 += d * d; }
  sse2 = wave_sum(sse2);
  __syncthreads();
  if(lane == 0) red[w] = sse2;
  __syncthreads();
  float inv2 = 1.f / (sqrtf((red[0] + red[1] + red[2] + red[3]) * (1.f / 2047.f)) + LN_EPS);
  #pragma unroll
  for(int q = 0; q < 8; ++q){
    int e = tid + 256 * q;
    float ncn = lncg[e] * (nc[q] - mean2) * inv2 + lncb[e];
    out[b * 2048 + e]           = tanh_f(ncn) * os[q];  // new_h
    out[1048576 + b * 2048 + e] = ncn;                  // new_c
  }
}

// =====================================================================
extern "C" void kernel_launch(void* const* d_in, const int* in_sizes, int n_in,
                              void* d_out, int out_size, void* d_ws, size_t ws_size,
                              hipStream_t stream){
  const float* x        = (const float*)d_in[0];
  const float* h        = (const float*)d_in[1];
  const float* c        = (const float*)d_in[2];
  const float* hyper_h  = (const float*)d_in[3];
  const float* hyper_c  = (const float*)d_in[4];
  const float* hc_Wih   = (const float*)d_in[5];
  const float* hc_bih   = (const float*)d_in[6];
  const float* hc_Whh   = (const float*)d_in[7];
  const float* hc_lng   = (const float*)d_in[8];
  const float* hc_lnb   = (const float*)d_in[9];
  const float* hc_lncg  = (const float*)d_in[10];
  const float* hc_lncb  = (const float*)d_in[11];
  const float* Wph      = (const float*)d_in[12];
  const float* bph      = (const float*)d_in[13];
  const float* Wpx      = (const float*)d_in[14];
  const float* bpx      = (const float*)d_in[15];
  const float* Wpb      = (const float*)d_in[16];
  const float* Wsh      = (const float*)d_in[17];
  const float* Wsx      = (const float*)d_in[18];
  const float* Wsb      = (const float*)d_in[19];
  const float* Wih      = (const float*)d_in[20];
  const float* Whh      = (const float*)d_in[21];
  const float* bias     = (const float*)d_in[22];
  const float* ln_g     = (const float*)d_in[23];
  const float* ln_b     = (const float*)d_in[24];
  const float* lnc_g    = (const float*)d_in[25];
  const float* lnc_b    = (const float*)d_in[26];

  float* out = (float*)d_out;
  // ws: v1 bf16 1MB | v2 bf16 1MB | P f32 1.5MB | g1 bf16 8.4MB | g2 bf16 8.4MB (~20.3MB)
  unsigned short* ws_v1 = (unsigned short*)d_ws;            // 512*1024
  unsigned short* ws_v2 = ws_v1 + 524288;                   // 512*1024
  float*          ws_P  = (float*)(ws_v2 + 524288);         // 512*768
  unsigned short* ws_g1 = (unsigned short*)(ws_P + 393216); // 512*8192
  unsigned short* ws_g2 = ws_g1 + 4194304;                  // 512*8192
  const float* nhh = out + 2097152;                         // new_hyper_h region of d_out

  k1_hyper_gemm<<<1024, 256, 0, stream>>>(x, h, hyper_h, hc_Wih, hc_Whh, ws_v1, ws_v2);
  k2_hyper_cell<<<128, 256, 0, stream>>>(ws_v1, ws_v2, hc_bih, hyper_c, hc_lng, hc_lnb, hc_lncg, hc_lncb, out);
  k3_pmat<<<dim3(12, 8), 256, 0, stream>>>(nhh, Wph, Wpx, Wpb, bph, bpx, ws_P);
  k4_gates<<<512, 512, 0, stream>>>(x, h, Wih, Whh, bias, ws_P, Wsh, Wsx, Wsb, ws_g1, ws_g2);
  k5_cell<<<512, 256, 0, stream>>>(ws_g1, ws_g2, c, ln_g, ln_b, lnc_g, lnc_b, out);
}